// Round 5
// baseline (2746.350 us; speedup 1.0000x reference)
//
#include <hip/hip_runtime.h>
#include <hip/hip_fp16.h>

#define FIN 512
#define FHID 16
#define FOUT 40

// hardware packed-f16 atomic add, no return (avoids any CAS fallback)
__device__ __forceinline__ void pk_add_f16(__half2* p, __half2 v) {
    asm volatile("global_atomic_pk_add_f16 %0, %1, off" :: "v"(p), "v"(v) : "memory");
}

// ---------------- degree ----------------

__global__ void k_count(const int* __restrict__ dst, int* __restrict__ cnt, int E) {
    int e = blockIdx.x * blockDim.x + threadIdx.x;
    if (e < E) atomicAdd(&cnt[dst[e]], 1);
}

__global__ void k_rsqrt(const int* __restrict__ cnt, float* __restrict__ dinv, int n) {
    int i = blockIdx.x * blockDim.x + threadIdx.x;
    if (i < n) dinv[i] = rsqrtf((float)(cnt[i] + 1));  // +1 self-loop
}

// ---------------- layer 1 GEMM: g = agg = fp16((x @ W1) * dinv) ----------------

__global__ __launch_bounds__(256) void k_gemm1(const float* __restrict__ x,
                                               const float* __restrict__ W1,
                                               const float* __restrict__ dinv,
                                               __half* __restrict__ g,
                                               __half* __restrict__ agg, int n) {
    __shared__ float Wl[FIN * FHID];  // 32 KiB
    {
        const float4* Wv = reinterpret_cast<const float4*>(W1);
        float4* Lv = reinterpret_cast<float4*>(Wl);
        for (int i = threadIdx.x; i < FIN * FHID / 4; i += 256) Lv[i] = Wv[i];
    }
    __syncthreads();

    int row = blockIdx.x * 256 + threadIdx.x;
    int r = row < n ? row : 0;
    const float4* xr = reinterpret_cast<const float4*>(x + (size_t)r * FIN);

    float acc[FHID];
#pragma unroll
    for (int o = 0; o < FHID; ++o) acc[o] = 0.0f;

#pragma unroll 1
    for (int kt = 0; kt < FIN / 32; ++kt) {
        float4 xv[8];
#pragma unroll
        for (int j = 0; j < 8; ++j) xv[j] = xr[kt * 8 + j];
#pragma unroll
        for (int j = 0; j < 8; ++j) {
#pragma unroll
            for (int q = 0; q < 4; ++q) {
                float xs = (&xv[j].x)[q];
                const float* wrow = &Wl[(kt * 32 + j * 4 + q) * FHID];
#pragma unroll
                for (int o = 0; o < FHID; ++o) acc[o] = fmaf(xs, wrow[o], acc[o]);
            }
        }
    }

    if (row < n) {
        float dv = dinv[row];
        __half2* gp = reinterpret_cast<__half2*>(g + (size_t)row * FHID);
        __half2* ap = reinterpret_cast<__half2*>(agg + (size_t)row * FHID);
#pragma unroll
        for (int q = 0; q < FHID / 2; ++q) {
            __half2 h = __floats2half2_rn(acc[2 * q] * dv, acc[2 * q + 1] * dv);
            gp[q] = h;
            ap[q] = h;  // self-loop init
        }
    }
}

// ---------------- edge scatter: agg[dst] += g[src], 1 thread/edge, 8 pk-f16 atomics --

__global__ __launch_bounds__(256) void k_scat(const int* __restrict__ src,
                                              const int* __restrict__ dst,
                                              const __half* __restrict__ g,
                                              __half* __restrict__ agg, int E) {
    int e = blockIdx.x * 256 + threadIdx.x;
    if (e >= E) return;
    int s = src[e], d = dst[e];
    const __half2* gr = reinterpret_cast<const __half2*>(g + (size_t)s * FHID);
    __half2* ar = reinterpret_cast<__half2*>(agg + (size_t)d * FHID);
    __half2 m[8];
#pragma unroll
    for (int j = 0; j < 8; ++j) m[j] = gr[j];
#pragma unroll
    for (int j = 0; j < 8; ++j) pk_add_f16(&ar[j], m[j]);
    asm volatile("s_waitcnt vmcnt(0)" ::: "memory");  // drain asm-issued atomics
}

// ---------------- finish layer 1: p = aggp = fp16(relu(agg*dinv + b1) * dinv) -------

__global__ void k_finish1(const __half* __restrict__ agg, const float* __restrict__ dinv,
                          const float* __restrict__ b1, __half* __restrict__ p,
                          __half* __restrict__ aggp, int n) {
    int nd = blockIdx.x * blockDim.x + threadIdx.x;
    if (nd >= n) return;
    float dv = dinv[nd];
    const __half2* ar = reinterpret_cast<const __half2*>(agg + (size_t)nd * FHID);
    __half2* pp = reinterpret_cast<__half2*>(p + (size_t)nd * FHID);
    __half2* ap = reinterpret_cast<__half2*>(aggp + (size_t)nd * FHID);
#pragma unroll
    for (int j = 0; j < FHID / 2; ++j) {
        float2 v = __half22float2(ar[j]);
        float a = fmaxf(fmaf(v.x, dv, b1[2 * j + 0]), 0.0f) * dv;
        float b = fmaxf(fmaf(v.y, dv, b1[2 * j + 1]), 0.0f) * dv;
        __half2 h = __floats2half2_rn(a, b);
        pp[j] = h;
        ap[j] = h;  // self-loop init for layer 2
    }
}

// ---------------- finish layer 2: out = log_softmax((aggp*dinv) @ W2 + b2) ----------

__global__ __launch_bounds__(256) void k_finish2(const __half* __restrict__ aggp,
                                                 const float* __restrict__ dinv,
                                                 const float* __restrict__ W2,
                                                 const float* __restrict__ b2,
                                                 float* __restrict__ out, int n) {
    __shared__ float Wl[FHID * FOUT];
    __shared__ float bl[FOUT];
    for (int i = threadIdx.x; i < FHID * FOUT; i += 256) Wl[i] = W2[i];
    if (threadIdx.x < FOUT) bl[threadIdx.x] = b2[threadIdx.x];
    __syncthreads();

    int nd = blockIdx.x * 256 + threadIdx.x;
    if (nd >= n) return;

    float dv = dinv[nd];
    float q[FHID];
    const __half2* ap = reinterpret_cast<const __half2*>(aggp + (size_t)nd * FHID);
#pragma unroll
    for (int j = 0; j < FHID / 2; ++j) {
        float2 v = __half22float2(ap[j]);
        q[2 * j + 0] = v.x * dv;
        q[2 * j + 1] = v.y * dv;
    }

    float acc[FOUT];
#pragma unroll
    for (int o = 0; o < FOUT; ++o) acc[o] = bl[o];
#pragma unroll
    for (int k = 0; k < FHID; ++k) {
        float qs = q[k];
        const float* wrow = &Wl[k * FOUT];
#pragma unroll
        for (int o = 0; o < FOUT; ++o) acc[o] = fmaf(qs, wrow[o], acc[o]);
    }

    float m = acc[0];
#pragma unroll
    for (int o = 1; o < FOUT; ++o) m = fmaxf(m, acc[o]);
    float ssum = 0.0f;
#pragma unroll
    for (int o = 0; o < FOUT; ++o) ssum += expf(acc[o] - m);
    float lse = m + logf(ssum);

    float4* op = reinterpret_cast<float4*>(out + (size_t)nd * FOUT);
#pragma unroll
    for (int t = 0; t < FOUT / 4; ++t) {
        float4 v;
        v.x = acc[4 * t + 0] - lse;
        v.y = acc[4 * t + 1] - lse;
        v.z = acc[4 * t + 2] - lse;
        v.w = acc[4 * t + 3] - lse;
        op[t] = v;
    }
}

// ---------------- launch ----------------

extern "C" void kernel_launch(void* const* d_in, const int* in_sizes, int n_in,
                              void* d_out, int out_size, void* d_ws, size_t ws_size,
                              hipStream_t stream) {
    const float* x  = (const float*)d_in[0];
    const int*   ei = (const int*)d_in[1];
    const float* W1 = (const float*)d_in[2];
    const float* b1 = (const float*)d_in[3];
    const float* W2 = (const float*)d_in[4];
    const float* b2 = (const float*)d_in[5];

    const int fh = in_sizes[3];              // 16
    const int fi = in_sizes[2] / fh;         // 512
    const int n  = in_sizes[0] / fi;         // 100000
    const int E  = in_sizes[1] / 2;          // 3200000
    (void)n_in; (void)out_size; (void)ws_size;

    const int* src = ei;
    const int* dst = ei + E;

    // workspace (all offsets 32B-aligned: n*4 = 400000 is a multiple of 32)
    char* w = (char*)d_ws;
    int*    cnt  = (int*)w;     w += (size_t)n * 4;
    float*  dinv = (float*)w;   w += (size_t)n * 4;
    __half* g    = (__half*)w;  w += (size_t)n * FHID * 2;
    __half* agg  = (__half*)w;  w += (size_t)n * FHID * 2;
    __half* p    = (__half*)w;  w += (size_t)n * FHID * 2;
    __half* aggp = (__half*)w;

    float* out = (float*)d_out;

    const int TB = 256;
    const int nb_e = (E + TB - 1) / TB;
    const int nb_n = (n + TB - 1) / TB;

    hipMemsetAsync(cnt, 0, (size_t)n * 4, stream);
    k_count<<<nb_e, TB, 0, stream>>>(dst, cnt, E);
    k_rsqrt<<<nb_n, TB, 0, stream>>>(cnt, dinv, n);

    k_gemm1<<<nb_n, TB, 0, stream>>>(x, W1, dinv, g, agg, n);
    k_scat<<<nb_e, TB, 0, stream>>>(src, dst, g, agg, E);
    k_finish1<<<nb_n, TB, 0, stream>>>(agg, dinv, b1, p, aggp, n);
    k_scat<<<nb_e, TB, 0, stream>>>(src, dst, p, aggp, E);
    k_finish2<<<nb_n, TB, 0, stream>>>(aggp, dinv, W2, b2, out, n);
}

// Round 6
// 558.990 us; speedup vs baseline: 4.9131x; 4.9131x over previous
//
#include <hip/hip_runtime.h>

#define FIN 512
#define FHID 16
#define FOUT 40

// ---------------- degree ----------------

__global__ void k_count(const int* __restrict__ dst, int* __restrict__ cnt, int E) {
    int e = blockIdx.x * blockDim.x + threadIdx.x;
    if (e < E) atomicAdd(&cnt[dst[e]], 1);
}

__global__ void k_rsqrt(const int* __restrict__ cnt, float* __restrict__ dinv, int n) {
    int i = blockIdx.x * blockDim.x + threadIdx.x;
    if (i < n) dinv[i] = rsqrtf((float)(cnt[i] + 1));  // +1 self-loop
}

// ---------------- layer 1 GEMM: g = agg = (x @ W1) * dinv ----------------

__global__ __launch_bounds__(256) void k_gemm1(const float* __restrict__ x,
                                               const float* __restrict__ W1,
                                               const float* __restrict__ dinv,
                                               float* __restrict__ g,
                                               float* __restrict__ agg, int n) {
    __shared__ float Wl[FIN * FHID];  // 32 KiB
    {
        const float4* Wv = reinterpret_cast<const float4*>(W1);
        float4* Lv = reinterpret_cast<float4*>(Wl);
        for (int i = threadIdx.x; i < FIN * FHID / 4; i += 256) Lv[i] = Wv[i];
    }
    __syncthreads();

    int row = blockIdx.x * 256 + threadIdx.x;
    int r = row < n ? row : 0;
    const float4* xr = reinterpret_cast<const float4*>(x + (size_t)r * FIN);

    float acc[FHID];
#pragma unroll
    for (int o = 0; o < FHID; ++o) acc[o] = 0.0f;

#pragma unroll 1
    for (int kt = 0; kt < FIN / 32; ++kt) {
        float4 xv[8];
#pragma unroll
        for (int j = 0; j < 8; ++j) xv[j] = xr[kt * 8 + j];
#pragma unroll
        for (int j = 0; j < 8; ++j) {
#pragma unroll
            for (int q = 0; q < 4; ++q) {
                float xs = (&xv[j].x)[q];
                const float* wrow = &Wl[(kt * 32 + j * 4 + q) * FHID];
#pragma unroll
                for (int o = 0; o < FHID; ++o) acc[o] = fmaf(xs, wrow[o], acc[o]);
            }
        }
    }

    if (row < n) {
        float dv = dinv[row];
        float4* gp = reinterpret_cast<float4*>(g + (size_t)row * FHID);
        float4* ap = reinterpret_cast<float4*>(agg + (size_t)row * FHID);
#pragma unroll
        for (int q = 0; q < FHID / 4; ++q) {
            float4 v;
            v.x = acc[4 * q + 0] * dv;
            v.y = acc[4 * q + 1] * dv;
            v.z = acc[4 * q + 2] * dv;
            v.w = acc[4 * q + 3] * dv;
            gp[q] = v;
            ap[q] = v;  // self-loop init
        }
    }
}

// ---------------- edge scatter: agg[dst] += g[src], 16 threads/edge ----------------
// zero-valued messages are skipped (atomicAdd of 0 is a no-op): halves layer-2 ops.

__global__ __launch_bounds__(256) void k_scat(const int* __restrict__ src,
                                              const int* __restrict__ dst,
                                              const float* __restrict__ g,
                                              float* __restrict__ agg, int E) {
    long long tid = (long long)blockIdx.x * 256 + threadIdx.x;
    int e = (int)(tid >> 4);
    int c = (int)(tid & 15);
    if (e >= E) return;
    int s = src[e];
    int d = dst[e];
    float v = g[(size_t)s * FHID + c];
    if (v != 0.0f) atomicAdd(&agg[(size_t)d * FHID + c], v);
}

// ---------------- finish layer 1: p = aggp = relu(agg*dinv + b1) * dinv -------------

__global__ void k_finish1(const float* __restrict__ agg, const float* __restrict__ dinv,
                          const float* __restrict__ b1, float* __restrict__ p,
                          float* __restrict__ aggp, int n) {
    int nd = blockIdx.x * blockDim.x + threadIdx.x;
    if (nd >= n) return;
    float dv = dinv[nd];
    const float4* ar = reinterpret_cast<const float4*>(agg + (size_t)nd * FHID);
    float4* pp = reinterpret_cast<float4*>(p + (size_t)nd * FHID);
    float4* ap = reinterpret_cast<float4*>(aggp + (size_t)nd * FHID);
    const float4* bv = reinterpret_cast<const float4*>(b1);
#pragma unroll
    for (int j = 0; j < FHID / 4; ++j) {
        float4 v = ar[j];
        float4 b = bv[j];
        float4 r;
        r.x = fmaxf(fmaf(v.x, dv, b.x), 0.0f) * dv;
        r.y = fmaxf(fmaf(v.y, dv, b.y), 0.0f) * dv;
        r.z = fmaxf(fmaf(v.z, dv, b.z), 0.0f) * dv;
        r.w = fmaxf(fmaf(v.w, dv, b.w), 0.0f) * dv;
        pp[j] = r;
        ap[j] = r;  // self-loop init for layer 2
    }
}

// ---------------- finish layer 2: out = log_softmax((aggp*dinv) @ W2 + b2) ----------

__global__ __launch_bounds__(256) void k_finish2(const float* __restrict__ aggp,
                                                 const float* __restrict__ dinv,
                                                 const float* __restrict__ W2,
                                                 const float* __restrict__ b2,
                                                 float* __restrict__ out, int n) {
    __shared__ float Wl[FHID * FOUT];
    __shared__ float bl[FOUT];
    for (int i = threadIdx.x; i < FHID * FOUT; i += 256) Wl[i] = W2[i];
    if (threadIdx.x < FOUT) bl[threadIdx.x] = b2[threadIdx.x];
    __syncthreads();

    int nd = blockIdx.x * 256 + threadIdx.x;
    if (nd >= n) return;

    float dv = dinv[nd];
    float q[FHID];
    const float4* ap = reinterpret_cast<const float4*>(aggp + (size_t)nd * FHID);
#pragma unroll
    for (int j = 0; j < FHID / 4; ++j) {
        float4 v = ap[j];
        q[4 * j + 0] = v.x * dv;
        q[4 * j + 1] = v.y * dv;
        q[4 * j + 2] = v.z * dv;
        q[4 * j + 3] = v.w * dv;
    }

    float acc[FOUT];
#pragma unroll
    for (int o = 0; o < FOUT; ++o) acc[o] = bl[o];
#pragma unroll
    for (int k = 0; k < FHID; ++k) {
        float qs = q[k];
        const float* wrow = &Wl[k * FOUT];
#pragma unroll
        for (int o = 0; o < FOUT; ++o) acc[o] = fmaf(qs, wrow[o], acc[o]);
    }

    float m = acc[0];
#pragma unroll
    for (int o = 1; o < FOUT; ++o) m = fmaxf(m, acc[o]);
    float ssum = 0.0f;
#pragma unroll
    for (int o = 0; o < FOUT; ++o) ssum += expf(acc[o] - m);
    float lse = m + logf(ssum);

    float4* op = reinterpret_cast<float4*>(out + (size_t)nd * FOUT);
#pragma unroll
    for (int t = 0; t < FOUT / 4; ++t) {
        float4 v;
        v.x = acc[4 * t + 0] - lse;
        v.y = acc[4 * t + 1] - lse;
        v.z = acc[4 * t + 2] - lse;
        v.w = acc[4 * t + 3] - lse;
        op[t] = v;
    }
}

// ---------------- launch ----------------

extern "C" void kernel_launch(void* const* d_in, const int* in_sizes, int n_in,
                              void* d_out, int out_size, void* d_ws, size_t ws_size,
                              hipStream_t stream) {
    const float* x  = (const float*)d_in[0];
    const int*   ei = (const int*)d_in[1];
    const float* W1 = (const float*)d_in[2];
    const float* b1 = (const float*)d_in[3];
    const float* W2 = (const float*)d_in[4];
    const float* b2 = (const float*)d_in[5];

    const int fh = in_sizes[3];              // 16
    const int fi = in_sizes[2] / fh;         // 512
    const int n  = in_sizes[0] / fi;         // 100000
    const int E  = in_sizes[1] / 2;          // 3200000
    (void)n_in; (void)out_size; (void)ws_size;

    const int* src = ei;
    const int* dst = ei + E;

    char* w = (char*)d_ws;
    int*   cnt  = (int*)w;    w += (size_t)n * 4;
    float* dinv = (float*)w;  w += (size_t)n * 4;
    float* g    = (float*)w;  w += (size_t)n * FHID * 4;
    float* agg  = (float*)w;  w += (size_t)n * FHID * 4;
    float* p    = (float*)w;  w += (size_t)n * FHID * 4;
    float* aggp = (float*)w;

    float* out = (float*)d_out;

    const int TB = 256;
    const int nb_e = (E + TB - 1) / TB;
    const int nb_n = (n + TB - 1) / TB;
    const int nb_s = (int)(((long long)E * FHID + TB - 1) / TB);

    hipMemsetAsync(cnt, 0, (size_t)n * 4, stream);
    k_count<<<nb_e, TB, 0, stream>>>(dst, cnt, E);
    k_rsqrt<<<nb_n, TB, 0, stream>>>(cnt, dinv, n);

    k_gemm1<<<nb_n, TB, 0, stream>>>(x, W1, dinv, g, agg, n);
    k_scat<<<nb_s, TB, 0, stream>>>(src, dst, g, agg, E);
    k_finish1<<<nb_n, TB, 0, stream>>>(agg, dinv, b1, p, aggp, n);
    k_scat<<<nb_s, TB, 0, stream>>>(src, dst, p, aggp, E);
    k_finish2<<<nb_n, TB, 0, stream>>>(aggp, dinv, W2, b2, out, n);
}